// Round 6
// baseline (9140.373 us; speedup 1.0000x reference)
//
#include <hip/hip_runtime.h>
#include <math.h>

#define EDGES 360000
#define NODES 30000

typedef _Float16 h2 __attribute__((ext_vector_type(2)));
typedef _Float16 h8 __attribute__((ext_vector_type(8)));

__device__ inline int imin(int a, int b){ return a < b ? a : b; }
__device__ inline int imax(int a, int b){ return a > b ? a : b; }
__device__ inline void atomAddF(float* p, float v){ unsafeAtomicAdd(p, v); }

__device__ __forceinline__ float fdot2h(h2 a, h2 b, float c){
#if __has_builtin(__builtin_amdgcn_fdot2)
  return __builtin_amdgcn_fdot2(a, b, c, false);
#else
  return c + (float)a[0]*(float)b[0] + (float)a[1]*(float)b[1];
#endif
}

__device__ __forceinline__ float softplusf(float v){
  return fmaxf(v, 0.f) + log1pf(expf(-fabsf(v)));
}

// ======================= Wigner-3j (CG) on-device init ======================

struct cplx { double re, im; };
__device__ inline cplx cmul(cplx a, cplx b){ return { a.re*b.re - a.im*b.im, a.re*b.im + a.im*b.re }; }

__device__ __constant__ double FACT[9] = {1.0,1.0,2.0,6.0,24.0,120.0,720.0,5040.0,40320.0};

__device__ double su2_cg(int j1,int m1,int j2,int m2,int j3,int m3){
  if (m3 != m1 + m2) return 0.0;
  int vmin = imax(imax(-j1 + j2 + m3, -j1 + m1), 0);
  int vmax = imin(imin(j2 + j3 + m1, j3 - j1 + j2), j3 + m3);
  if (vmax < vmin) return 0.0;
  double c = sqrt((2.0*j3 + 1.0) * FACT[j3+j1-j2] * FACT[j3-j1+j2] * FACT[j1+j2-j3]
                  * FACT[j3+m3] * FACT[j3-m3]
                  / (FACT[j1+j2+j3+1] * FACT[j1-m1] * FACT[j1+m1] * FACT[j2-m2] * FACT[j2+m2]));
  double s = 0.0;
  for (int v = vmin; v <= vmax; ++v){
    double t = FACT[j2+j3+m1-v] * FACT[j1-m1+v]
             / (FACT[v] * FACT[j3-j1+j2-v] * FACT[j3+m3-v] * FACT[v+j1-j2-m3]);
    s += (((v + j2 + m2) & 1) ? -t : t);
  }
  return c * s;
}

__device__ cplx qval(int l, int r, int c){
  const double s = 0.7071067811865476;
  int m = r - l;
  cplx v = {0.0, 0.0};
  if (m < 0){
    if      (c == l - m) v = { s, 0.0 };
    else if (c == l + m) v = { 0.0, -s };
  } else if (m == 0){
    if (c == l) v = { 1.0, 0.0 };
  } else {
    double sg = (m & 1) ? -1.0 : 1.0;
    if      (c == l + m) v = { sg*s, 0.0 };
    else if (c == l - m) v = { 0.0, sg*s };
  }
  switch (l & 3){
    case 0: return v;
    case 1: return {  v.im, -v.re };
    case 2: return { -v.re, -v.im };
    default:return { -v.im,  v.re };
  }
}

struct Combo { int l1, l2, l3, off; };
__device__ __constant__ Combo COMBOS[18] = {
  {0,0,0,0},{0,1,1,1},{0,2,2,10},{1,0,1,35},{1,1,0,44},{1,1,1,53},{1,1,2,80},
  {1,2,1,125},{1,2,2,170},{1,2,3,245},{2,0,2,350},{2,1,1,375},{2,1,2,420},
  {2,1,3,495},{2,2,0,600},{2,2,1,625},{2,2,2,700},{2,2,3,825}
};

__global__ void init_cg_kernel(float* __restrict__ cg){
  __shared__ double sr[175], si[175];
  __shared__ double snorm[2];
  const Combo cb = COMBOS[blockIdx.x];
  const int d1 = 2*cb.l1+1, d2 = 2*cb.l2+1, d3 = 2*cb.l3+1;
  const int tot = d1*d2*d3;
  for (int idx = threadIdx.x; idx < tot; idx += blockDim.x){
    int j = idx/(d2*d3), rem = idx - j*(d2*d3);
    int l = rem/d3, m = rem - l*d3;
    double ar = 0.0, ai = 0.0;
    for (int i = 0; i < d1; ++i){
      cplx q1 = qval(cb.l1, i, j);
      if (q1.re == 0.0 && q1.im == 0.0) continue;
      for (int k = 0; k < d2; ++k){
        cplx q2 = qval(cb.l2, k, l);
        if (q2.re == 0.0 && q2.im == 0.0) continue;
        cplx q12 = cmul(q1, q2);
        for (int n = 0; n < d3; ++n){
          double g = su2_cg(cb.l1, i-cb.l1, cb.l2, k-cb.l2, cb.l3, n-cb.l3);
          if (g == 0.0) continue;
          cplx q3 = qval(cb.l3, n, m); q3.im = -q3.im;
          cplx t = cmul(q12, q3);
          ar += t.re * g; ai += t.im * g;
        }
      }
    }
    sr[idx] = ar; si[idx] = ai;
  }
  __syncthreads();
  if (threadIdx.x == 0){
    double nr = 0.0, ni = 0.0;
    for (int t = 0; t < tot; ++t){ nr += sr[t]*sr[t]; ni += si[t]*si[t]; }
    snorm[0] = nr; snorm[1] = ni;
  }
  __syncthreads();
  const bool useR = snorm[0] >= snorm[1];
  const double inv = 1.0 / sqrt(useR ? snorm[0] : snorm[1]);
  for (int idx = threadIdx.x; idx < tot; idx += blockDim.x)
    cg[cb.off + idx] = (float)((useR ? sr[idx] : si[idx]) * inv);
}

// ======================= layer definitions =================================

struct InsT { int l1,l2,l3,m1,m3,s1,s2,so,woff,cg; float alpha; };

struct L1 {
  static constexpr int NIN = 16, NOUT = 32, WN = 320, NI = 3, NU = 16;
  static constexpr InsT ins[NI] = {
    {0,0,0,16,16, 0,0, 0,   0,  0, 0.25f},
    {0,1,1,16, 2, 0,1,16, 256,  1, 0.4330127019f},
    {0,2,2,16, 2, 0,4,22, 288, 10, 0.5590169944f},
  };
  static constexpr int uT [NU] = {0,0,0,0,0,0,0,0, 1,1,1,1, 2,2,2,2};
  static constexpr int uCh[NU] = {0,1,2,3,4,5,6,7, 0,1,2,3, 0,1,2,3};
  static constexpr int uD0[NU] = {0,0,0,0,0,0,0,0, 0,0,0,0, 0,0,0,0};
  static constexpr int uND[NU] = {2,2,2,2,2,2,2,2, 4,4,4,4, 4,4,4,4};
  static constexpr int uSl[NU] = {0,1,2,3,0,1,2,3, 0,1,2,3, 0,1,2,3};
};
struct L2 {
  static constexpr int NIN = 32, NOUT = 48, WN = 424, NI = 15, NU = 30;
  static constexpr InsT ins[NI] = {
    {0,0,0,16,16, 0,0, 0,   0,  0, 0.2236067977f},
    {0,1,1,16, 2, 0,1,16, 256,  1, 0.3692744729f},
    {0,2,2,16, 2, 0,4,28, 288, 10, 0.4767312946f},
    {1,0,1, 2, 2,16,0,16, 320, 35, 0.3692744729f},
    {1,1,0, 2,16,16,1, 0, 324, 44, 0.2236067977f},
    {1,1,1, 2, 2,16,1,22, 356, 53, 0.8660254038f},
    {1,1,2, 2, 2,16,1,28, 360, 80, 0.4767312946f},
    {1,2,1, 2, 2,16,4,16, 364,125, 0.3692744729f},
    {1,2,2, 2, 2,16,4,38, 368,170, 1.1180339887f},
    {2,0,2, 2, 2,22,0,28, 372,350, 0.4767312946f},
    {2,1,1, 2, 2,22,1,16, 376,375, 0.3692744729f},
    {2,1,2, 2, 2,22,1,38, 380,420, 1.1180339887f},
    {2,2,0, 2,16,22,4, 0, 384,600, 0.2236067977f},
    {2,2,1, 2, 2,22,4,22, 416,625, 0.8660254038f},
    {2,2,2, 2, 2,22,4,28, 420,700, 0.4767312946f},
  };
  static constexpr int uT [NU] = {0,0,0,0,0,0,0,0, 1,1,1,1, 2,2,2,2, 3, 4,4, 5, 6,7,8, 9,10,11, 12,12, 13,14};
  static constexpr int uCh[NU] = {0,1,2,3,4,5,6,7, 0,1,2,3, 0,1,2,3, 0, 0,0, 0, 0,0,0, 0,0,0, 0,0, 0,0};
  static constexpr int uD0[NU] = {0,0,0,0,0,0,0,0, 0,0,0,0, 0,0,0,0, 0, 0,1, 0, 0,0,0, 0,0,0, 0,1, 0,0};
  static constexpr int uND[NU] = {2,2,2,2,2,2,2,2, 4,4,4,4, 4,4,4,4, 2, 1,1, 2, 2,2,2, 2,2,2, 1,1, 2,2};
  static constexpr int uSl[NU] = {0,1,2,3,0,1,2,3, 0,1,2,3, 0,1,2,3, 0, 0,1, 1, 2,2,2, 3,3,3, 2,3, 0,1};
};
struct L3 {
  static constexpr int NIN = 48, NOUT = 64, WN = 216, NI = 33, NU = 42;
  static constexpr InsT ins[NI] = {
    {0,0,0,16,2, 0,0, 0,   0,  0, 0.2236067977f},
    {0,1,1,16,2, 0,1,10,  32,  1, 0.3396831102f},
    {0,2,2,16,2, 0,4,16,  64, 10, 0.4385290097f},
    {1,0,1, 2,2,16,0,10,  96, 35, 0.3396831102f},
    {1,1,0, 2,2,16,1, 0, 100, 44, 0.2236067977f},
    {1,1,1, 2,2,16,1, 4, 104, 53, 0.5477225575f},
    {1,1,2, 2,2,16,1,16, 108, 80, 0.4385290097f},
    {1,2,1, 2,2,16,4,10, 112,125, 0.3396831102f},
    {1,2,2, 2,2,16,4,26, 116,170, 0.7071067812f},
    {1,2,3, 2,2,16,4,50, 120,245, 1.0801234497f},
    {1,0,1, 2,2,22,0, 4, 124, 35, 0.5477225575f},
    {1,1,0, 2,2,22,1, 2, 128, 44, 0.5f},
    {1,1,1, 2,2,22,1,10, 132, 53, 0.3396831102f},
    {1,1,2, 2,2,22,1,26, 136, 80, 0.7071067812f},
    {1,2,1, 2,2,22,4, 4, 140,125, 0.5477225575f},
    {1,2,2, 2,2,22,4,16, 144,170, 0.4385290097f},
    {1,2,3, 2,2,22,4,36, 148,245, 1.0801234497f},
    {2,0,2, 2,2,28,0,16, 152,350, 0.4385290097f},
    {2,1,1, 2,2,28,1,10, 156,375, 0.3396831102f},
    {2,1,2, 2,2,28,1,26, 160,420, 0.7071067812f},
    {2,1,3, 2,2,28,1,50, 164,495, 1.0801234497f},
    {2,2,0, 2,2,28,4, 0, 168,600, 0.2236067977f},
    {2,2,1, 2,2,28,4, 4, 172,625, 0.5477225575f},
    {2,2,2, 2,2,28,4,16, 176,700, 0.4385290097f},
    {2,2,3, 2,2,28,4,36, 180,825, 1.0801234497f},
    {2,0,2, 2,2,38,0,26, 184,350, 0.7071067812f},
    {2,1,1, 2,2,38,1, 4, 188,375, 0.5477225575f},
    {2,1,2, 2,2,38,1,16, 192,420, 0.4385290097f},
    {2,1,3, 2,2,38,1,36, 196,495, 1.0801234497f},
    {2,2,0, 2,2,38,4, 2, 200,600, 0.5f},
    {2,2,1, 2,2,38,4,10, 204,625, 0.3396831102f},
    {2,2,2, 2,2,38,4,26, 208,700, 0.7071067812f},
    {2,2,3, 2,2,38,4,50, 212,825, 1.0801234497f},
  };
  static constexpr int uT [NU] = {0,0,0,0, 1,1,1,1, 2,2,2,2,
    3,4,5,6,7,8,9,10,11,12,13,14,15,16,17,18,19,20,21,22,23,24,25,26,27,28,29,30,31,32};
  static constexpr int uCh[NU] = {0,1,2,3, 0,1,2,3, 0,1,2,3,
    0,0,0,0,0,0,0,0,0,0,0,0,0,0,0,0,0,0,0,0,0,0,0,0,0,0,0,0,0,0};
  static constexpr int uD0[NU] = {0,0,0,0, 0,0,0,0, 0,0,0,0,
    0,0,0,0,0,0,0,0,0,0,0,0,0,0,0,0,0,0,0,0,0,0,0,0,0,0,0,0,0,0};
  static constexpr int uND[NU] = {4,4,4,4, 4,4,4,4, 4,4,4,4,
    2,2,2,2,2,2,2,2,2,2,2,2,2,2,2,2,2,2,2,2,2,2,2,2,2,2,2,2,2,2};
  static constexpr int uSl[NU] = {0,1,2,3, 0,1,2,3, 0,1,2,3,
    0,1,2,3,0,1,2,3,0,1,2,3,0,1,2,3,0,1,2,3,0,1,2,3,0,1,2,3,0,1};
};

// ======================= constexpr checks / helpers ========================

template<class LD>
constexpr int colsum(){
  int s = 0;
  for (int u = 0; u < LD::NU; ++u) s += LD::uND[u] * LD::ins[LD::uT[u]].m3;
  return s;
}
static_assert(colsum<L1>() == L1::WN, "L1 col coverage");
static_assert(colsum<L2>() == L2::WN, "L2 col coverage");
static_assert(colsum<L3>() == L3::WN, "L3 col coverage");

template<class LD>
constexpr bool touchedf(int slot, int o){
  for (int u = 0; u < LD::NU; ++u){
    if (LD::uSl[u] != slot) continue;
    const InsT I = LD::ins[LD::uT[u]];
    if (o >= I.so && o < I.so + I.m3 * (2*I.l3 + 1)) return true;
  }
  return false;
}

// ======================= fused FC2+TP units (barrier-free) =================

template<class LD, int SLOT, int U>
__device__ __forceinline__ void tpfc2(const int le,
    const float* __restrict__ hidF,
    const float* __restrict__ w2, const float* __restrict__ b2,
    const float* __restrict__ cgp, const float* __restrict__ arow_g,
    const float (&sh)[9], float (&outv)[LD::NOUT])
{
  if constexpr (U < LD::NU) {
    if constexpr (LD::uSl[U] == SLOT) {
      constexpr InsT I = LD::ins[LD::uT[U]];
      constexpr int d1 = 2*I.l1+1, d2 = 2*I.l2+1, d3 = 2*I.l3+1;
      constexpr int UCH = (I.m3 == 16) ? 2 : (I.m1 == 16 ? 4 : 2);
      constexpr int ND = LD::uND[U], D0 = LD::uD0[U];
      constexpr int cbase = I.woff + LD::uCh[U]*UCH*I.m3 + D0*I.m3;
      constexpr int NW = ND * I.m3;
      // ---- ab precompute (alpha folded), per du ----
      float ab[ND][d3];
      #pragma unroll
      for (int dd = 0; dd < ND; ++dd) {
        const int u = LD::uCh[U]*UCH + D0 + dd;
        float tk[d3];
        #pragma unroll
        for (int k = 0; k < d3; ++k) tk[k] = 0.f;
        #pragma unroll
        for (int i = 0; i < d1; ++i) {
          const float ai = arow_g[I.s1 + u*d1 + i];
          #pragma unroll
          for (int j = 0; j < d2; ++j) {
            const float s = ai * sh[I.s2 + j];
            #pragma unroll
            for (int k = 0; k < d3; ++k)
              tk[k] = fmaf(cgp[I.cg + (i*d2 + j)*d3 + k], s, tk[k]);
          }
        }
        #pragma unroll
        for (int k = 0; k < d3; ++k) ab[dd][k] = I.alpha * tk[k];
      }
      // ---- FC2 for this unit's columns (fp32, wave-uniform w2 reads) ----
      float wacc[NW];
      #pragma unroll
      for (int p = 0; p < NW; ++p) wacc[p] = b2[cbase + p];
      for (int h = 0; h < 64; ++h) {
        const float hv = hidF[h*68 + le];
        const float* __restrict__ wr = w2 + (size_t)h*LD::WN + cbase;
        #pragma unroll
        for (int p = 0; p < NW; ++p) wacc[p] = fmaf(hv, wr[p], wacc[p]);
      }
      // ---- apply ----
      #pragma unroll
      for (int dd = 0; dd < ND; ++dd)
        #pragma unroll
        for (int wo = 0; wo < I.m3; ++wo)
          #pragma unroll
          for (int k = 0; k < d3; ++k)
            outv[I.so + wo*d3 + k] = fmaf(wacc[dd*I.m3 + wo], ab[dd][k],
                                          outv[I.so + wo*d3 + k]);
    }
    tpfc2<LD, SLOT, U+1>(le, hidF, w2, b2, cgp, arow_g, sh, outv);
  }
}

template<class LD, int SLOT, int O>
__device__ __forceinline__ void scat(float* dp, const float (&outv)[LD::NOUT]){
  if constexpr (O < LD::NOUT) {
    if constexpr (touchedf<LD>(SLOT, O)) atomAddF(dp + O, outv[O]);
    scat<LD, SLOT, O+1>(dp, outv);
  }
}

// ======================= per-slot tail (NO barriers inside) ================

template<class LD, int SLOT>
__device__ __forceinline__ void tail(const int t, const int e0g,
    const float* __restrict__ hidF, const float* __restrict__ node_h,
    const float* __restrict__ edge_vec, const int* __restrict__ eidx,
    const float* __restrict__ w2, const float* __restrict__ b2,
    const float* __restrict__ cgp, float* __restrict__ out_acc)
{
  const int le = t & 63;
  const int eme = e0g + le;
  const int src = eidx[eme];
  const int dst = eidx[EDGES + eme];
  const float* arow_g = node_h + (size_t)dst * LD::NIN;
  float sh[9];
  {
    const float vx = edge_vec[(size_t)eme*3 + 0];
    const float vy = edge_vec[(size_t)eme*3 + 1];
    const float vz = edge_vec[(size_t)eme*3 + 2];
    const float nrm = sqrtf(vx*vx + vy*vy + vz*vz);
    const float invn = 1.0f / fmaxf(nrm, 1e-12f);
    const float x = vx*invn, y = vy*invn, z = vz*invn;
    sh[0] = 1.0f;
    sh[1] = 1.7320508076f * y;
    sh[2] = 1.7320508076f * z;
    sh[3] = 1.7320508076f * x;
    sh[4] = 3.8729833462f * x * y;
    sh[5] = 3.8729833462f * y * z;
    sh[6] = 1.1180339887f * (3.0f*z*z - 1.0f);
    sh[7] = 3.8729833462f * x * z;
    sh[8] = 1.9364916731f * (x*x - y*y);
  }
  float outv[LD::NOUT];
  #pragma unroll
  for (int o = 0; o < LD::NOUT; ++o) outv[o] = 0.f;

  tpfc2<LD, SLOT, 0>(le, hidF, w2, b2, cgp, arow_g, sh, outv);

  float* dp = out_acc + (size_t)src * LD::NOUT;
  scat<LD, SLOT, 0>(dp, outv);
}

// ======================= fused conv kernel =================================

template<class LD>
__launch_bounds__(256, 2)
__global__ void conv_fused_kernel(const float* __restrict__ node_h,
    const float* __restrict__ edge_vec, const float* __restrict__ edge_feat,
    const int* __restrict__ eidx,
    const float* __restrict__ w1, const float* __restrict__ b1,
    const float* __restrict__ w2, const float* __restrict__ b2,
    const float* __restrict__ cgsrc, float* __restrict__ out_acc)
{
  __shared__ __align__(16) char sm[34816];
  float* hidF = (float*)sm;        // [64 h][68 e] fp32
  char* efsB = sm + 17408;         // [32 cp][272B] fp16 ef pairs (transposed)
  char* w1sB = sm + 26112;         // [32 cp][272B]

  const int t = threadIdx.x;
  const int e0g = blockIdx.x * 64;

  // ---------- phase 0: stage ef + w1 (fp16 pairs) ----------
  {
    const float4* efg = (const float4*)edge_feat + (size_t)e0g * 16;
    #pragma unroll
    for (int r = 0; r < 4; ++r) {
      const int f = r*256 + t;
      const float4 v = efg[f];
      const int e = f >> 4, c0 = (f & 15) * 4;
      h2 pa; pa[0] = (_Float16)v.x; pa[1] = (_Float16)v.y;
      h2 pb; pb[0] = (_Float16)v.z; pb[1] = (_Float16)v.w;
      *(h2*)(efsB + (c0>>1)*272 + e*4)     = pa;
      *(h2*)(efsB + ((c0>>1)+1)*272 + e*4) = pb;
    }
    const int cp = t >> 3, hq = t & 7, hb = hq*8;
    const float4 wa0 = *(const float4*)&w1[(size_t)(2*cp)*64 + hb];
    const float4 wa1 = *(const float4*)&w1[(size_t)(2*cp)*64 + hb + 4];
    const float4 wb0 = *(const float4*)&w1[(size_t)(2*cp+1)*64 + hb];
    const float4 wb1 = *(const float4*)&w1[(size_t)(2*cp+1)*64 + hb + 4];
    const float a0[8] = {wa0.x,wa0.y,wa0.z,wa0.w, wa1.x,wa1.y,wa1.z,wa1.w};
    const float b0[8] = {wb0.x,wb0.y,wb0.z,wb0.w, wb1.x,wb1.y,wb1.z,wb1.w};
    #pragma unroll
    for (int i = 0; i < 8; ++i) {
      h2 p; p[0] = (_Float16)a0[i]; p[1] = (_Float16)b0[i];
      *(h2*)(w1sB + cp*272 + (hb+i)*4) = p;
    }
  }
  __syncthreads();

  // ---------- phase 1: FC1 (fp16 dot2) -> hidF (fp32) ----------
  {
    const int hg = t >> 4, eg2 = t & 15;
    const int h0 = hg*4, e0 = eg2*4;
    float acc[4][4];
    const float4 b1v = *(const float4*)&b1[h0];
    const float bb[4] = {b1v.x, b1v.y, b1v.z, b1v.w};
    #pragma unroll
    for (int j = 0; j < 4; ++j)
      #pragma unroll
      for (int i = 0; i < 4; ++i) acc[j][i] = bb[j];
    #pragma unroll 4
    for (int cp = 0; cp < 32; ++cp) {
      const h8 ev = *(const h8*)(efsB + cp*272 + e0*4);
      const h8 wv = *(const h8*)(w1sB + cp*272 + h0*4);
      #pragma unroll
      for (int j = 0; j < 4; ++j)
        #pragma unroll
        for (int i = 0; i < 4; ++i)
          acc[j][i] = fdot2h(((const h2*)&wv)[j], ((const h2*)&ev)[i], acc[j][i]);
    }
    #pragma unroll
    for (int j = 0; j < 4; ++j) {
      float4 o;
      o.x = softplusf(acc[j][0]);
      o.y = softplusf(acc[j][1]);
      o.z = softplusf(acc[j][2]);
      o.w = softplusf(acc[j][3]);
      *(float4*)&hidF[(h0+j)*68 + e0] = o;
    }
  }
  __syncthreads();

  // ---------- phase 2: barrier-free slot-specialized FC2+TP+scatter ----------
  switch (t >> 6) {
    case 0:  tail<LD,0>(t, e0g, hidF, node_h, edge_vec, eidx, w2, b2, cgsrc, out_acc); break;
    case 1:  tail<LD,1>(t, e0g, hidF, node_h, edge_vec, eidx, w2, b2, cgsrc, out_acc); break;
    case 2:  tail<LD,2>(t, e0g, hidF, node_h, edge_vec, eidx, w2, b2, cgsrc, out_acc); break;
    default: tail<LD,3>(t, e0g, hidF, node_h, edge_vec, eidx, w2, b2, cgsrc, out_acc); break;
  }
}

// ======================= small kernels =====================================

__global__ void count_kernel(const int* __restrict__ eidx, float* __restrict__ cnt){
  const int e = blockIdx.x * 256 + threadIdx.x;
  if (e < EDGES) atomAddF(&cnt[eidx[e]], 1.0f);
}

__global__ void lin_kernel(const float* __restrict__ nf, const float* __restrict__ w,
                           const float* __restrict__ b, float* __restrict__ h0){
  const int idx = blockIdx.x * 256 + threadIdx.x;
  if (idx >= NODES * 16) return;
  const int n = idx >> 4, o = idx & 15;
  const float* __restrict__ row = nf + (size_t)n * 256;
  float acc = b[o];
  for (int c = 0; c < 256; ++c) acc = fmaf(row[c], w[c*16 + o], acc);
  h0[idx] = acc;
}

template<int NOUT, bool RES>
__global__ void node_finish_kernel(float* __restrict__ h, const float* __restrict__ cnt,
                                   const float* __restrict__ h0){
  const int idx = blockIdx.x * 256 + threadIdx.x;
  if (idx >= NODES * NOUT) return;
  const int n = idx / NOUT, o = idx - n * NOUT;
  float v = h[idx] / fmaxf(cnt[n], 1.0f);
  if (RES && o < 16) v += h0[n*16 + o];
  h[idx] = v;
}

// ======================= launch ============================================

extern "C" void kernel_launch(void* const* d_in, const int* in_sizes, int n_in,
                              void* d_out, int out_size, void* d_ws, size_t ws_size,
                              hipStream_t stream) {
  (void)in_sizes; (void)n_in; (void)out_size; (void)ws_size;
  const float* node_feature = (const float*)d_in[0];
  const float* edge_vec     = (const float*)d_in[1];
  const float* edge_feature = (const float*)d_in[2];
  const int*   edge_index   = (const int*)d_in[3];
  const float* lin_w = (const float*)d_in[4];
  const float* lin_b = (const float*)d_in[5];
  const float* f1w1 = (const float*)d_in[6];
  const float* f1b1 = (const float*)d_in[7];
  const float* f1w2 = (const float*)d_in[8];
  const float* f1b2 = (const float*)d_in[9];
  const float* f2w1 = (const float*)d_in[10];
  const float* f2b1 = (const float*)d_in[11];
  const float* f2w2 = (const float*)d_in[12];
  const float* f2b2 = (const float*)d_in[13];
  const float* f3w1 = (const float*)d_in[14];
  const float* f3b1 = (const float*)d_in[15];
  const float* f3w2 = (const float*)d_in[16];
  const float* f3b2 = (const float*)d_in[17];

  float* ws  = (float*)d_ws;
  float* cg  = ws;                 // 1000 floats (1024 reserved)
  float* cnt = ws + 1024;          // 30000
  float* h0  = ws + 32768;         // 30000*16
  float* h1  = h0 + 480000;        // 30000*32
  float* h2p = h1 + 960000;        // 30000*48
  float* outp = (float*)d_out;     // 30000*64

  (void)hipMemsetAsync(cnt, 0, NODES * sizeof(float), stream);
  (void)hipMemsetAsync(h1,  0, NODES * 32 * sizeof(float), stream);
  (void)hipMemsetAsync(h2p, 0, NODES * 48 * sizeof(float), stream);
  (void)hipMemsetAsync(outp,0, NODES * 64 * sizeof(float), stream);

  init_cg_kernel<<<18, 256, 0, stream>>>(cg);
  count_kernel<<<(EDGES + 255)/256, 256, 0, stream>>>(edge_index, cnt);
  lin_kernel<<<(NODES*16 + 255)/256, 256, 0, stream>>>(node_feature, lin_w, lin_b, h0);

  const int egrid = EDGES / 64;    // 5625, exact
  conv_fused_kernel<L1><<<egrid, 256, 0, stream>>>(h0, edge_vec, edge_feature, edge_index,
                                                   f1w1, f1b1, f1w2, f1b2, cg, h1);
  node_finish_kernel<32, true><<<(NODES*32 + 255)/256, 256, 0, stream>>>(h1, cnt, h0);

  conv_fused_kernel<L2><<<egrid, 256, 0, stream>>>(h1, edge_vec, edge_feature, edge_index,
                                                   f2w1, f2b1, f2w2, f2b2, cg, h2p);
  node_finish_kernel<48, false><<<(NODES*48 + 255)/256, 256, 0, stream>>>(h2p, cnt, h0);

  conv_fused_kernel<L3><<<egrid, 256, 0, stream>>>(h2p, edge_vec, edge_feature, edge_index,
                                                   f3w1, f3b1, f3w2, f3b2, cg, outp);
  node_finish_kernel<64, false><<<(NODES*64 + 255)/256, 256, 0, stream>>>(outp, cnt, h0);
}

// Round 7
// 1598.963 us; speedup vs baseline: 5.7164x; 5.7164x over previous
//
#include <hip/hip_runtime.h>
#include <math.h>

#define EDGES 360000
#define NODES 30000
#define NB_SCAN 118   // ceil(30000/256)

typedef _Float16 h2 __attribute__((ext_vector_type(2)));
typedef _Float16 h8 __attribute__((ext_vector_type(8)));

__device__ inline int imin(int a, int b){ return a < b ? a : b; }
__device__ inline int imax(int a, int b){ return a > b ? a : b; }

__device__ __forceinline__ float fdot2h(h2 a, h2 b, float c){
#if __has_builtin(__builtin_amdgcn_fdot2)
  return __builtin_amdgcn_fdot2(a, b, c, false);
#else
  return c + (float)a[0]*(float)b[0] + (float)a[1]*(float)b[1];
#endif
}

__device__ __forceinline__ float softplusf(float v){
  return fmaxf(v, 0.f) + log1pf(expf(-fabsf(v)));
}

// ======================= Wigner-3j (CG) on-device init ======================

struct cplx { double re, im; };
__device__ inline cplx cmul(cplx a, cplx b){ return { a.re*b.re - a.im*b.im, a.re*b.im + a.im*b.re }; }

__device__ __constant__ double FACT[9] = {1.0,1.0,2.0,6.0,24.0,120.0,720.0,5040.0,40320.0};

__device__ double su2_cg(int j1,int m1,int j2,int m2,int j3,int m3){
  if (m3 != m1 + m2) return 0.0;
  int vmin = imax(imax(-j1 + j2 + m3, -j1 + m1), 0);
  int vmax = imin(imin(j2 + j3 + m1, j3 - j1 + j2), j3 + m3);
  if (vmax < vmin) return 0.0;
  double c = sqrt((2.0*j3 + 1.0) * FACT[j3+j1-j2] * FACT[j3-j1+j2] * FACT[j1+j2-j3]
                  * FACT[j3+m3] * FACT[j3-m3]
                  / (FACT[j1+j2+j3+1] * FACT[j1-m1] * FACT[j1+m1] * FACT[j2-m2] * FACT[j2+m2]));
  double s = 0.0;
  for (int v = vmin; v <= vmax; ++v){
    double t = FACT[j2+j3+m1-v] * FACT[j1-m1+v]
             / (FACT[v] * FACT[j3-j1+j2-v] * FACT[j3+m3-v] * FACT[v+j1-j2-m3]);
    s += (((v + j2 + m2) & 1) ? -t : t);
  }
  return c * s;
}

__device__ cplx qval(int l, int r, int c){
  const double s = 0.7071067811865476;
  int m = r - l;
  cplx v = {0.0, 0.0};
  if (m < 0){
    if      (c == l - m) v = { s, 0.0 };
    else if (c == l + m) v = { 0.0, -s };
  } else if (m == 0){
    if (c == l) v = { 1.0, 0.0 };
  } else {
    double sg = (m & 1) ? -1.0 : 1.0;
    if      (c == l + m) v = { sg*s, 0.0 };
    else if (c == l - m) v = { 0.0, sg*s };
  }
  switch (l & 3){
    case 0: return v;
    case 1: return {  v.im, -v.re };
    case 2: return { -v.re, -v.im };
    default:return { -v.im,  v.re };
  }
}

struct Combo { int l1, l2, l3, off; };
__device__ __constant__ Combo COMBOS[18] = {
  {0,0,0,0},{0,1,1,1},{0,2,2,10},{1,0,1,35},{1,1,0,44},{1,1,1,53},{1,1,2,80},
  {1,2,1,125},{1,2,2,170},{1,2,3,245},{2,0,2,350},{2,1,1,375},{2,1,2,420},
  {2,1,3,495},{2,2,0,600},{2,2,1,625},{2,2,2,700},{2,2,3,825}
};

__global__ void init_cg_kernel(float* __restrict__ cg){
  __shared__ double sr[175], si[175];
  __shared__ double snorm[2];
  const Combo cb = COMBOS[blockIdx.x];
  const int d1 = 2*cb.l1+1, d2 = 2*cb.l2+1, d3 = 2*cb.l3+1;
  const int tot = d1*d2*d3;
  for (int idx = threadIdx.x; idx < tot; idx += blockDim.x){
    int j = idx/(d2*d3), rem = idx - j*(d2*d3);
    int l = rem/d3, m = rem - l*d3;
    double ar = 0.0, ai = 0.0;
    for (int i = 0; i < d1; ++i){
      cplx q1 = qval(cb.l1, i, j);
      if (q1.re == 0.0 && q1.im == 0.0) continue;
      for (int k = 0; k < d2; ++k){
        cplx q2 = qval(cb.l2, k, l);
        if (q2.re == 0.0 && q2.im == 0.0) continue;
        cplx q12 = cmul(q1, q2);
        for (int n = 0; n < d3; ++n){
          double g = su2_cg(cb.l1, i-cb.l1, cb.l2, k-cb.l2, cb.l3, n-cb.l3);
          if (g == 0.0) continue;
          cplx q3 = qval(cb.l3, n, m); q3.im = -q3.im;
          cplx t = cmul(q12, q3);
          ar += t.re * g; ai += t.im * g;
        }
      }
    }
    sr[idx] = ar; si[idx] = ai;
  }
  __syncthreads();
  if (threadIdx.x == 0){
    double nr = 0.0, ni = 0.0;
    for (int t = 0; t < tot; ++t){ nr += sr[t]*sr[t]; ni += si[t]*si[t]; }
    snorm[0] = nr; snorm[1] = ni;
  }
  __syncthreads();
  const bool useR = snorm[0] >= snorm[1];
  const double inv = 1.0 / sqrt(useR ? snorm[0] : snorm[1]);
  for (int idx = threadIdx.x; idx < tot; idx += blockDim.x)
    cg[cb.off + idx] = (float)((useR ? sr[idx] : si[idx]) * inv);
}

// ======================= layer definitions =================================

struct InsT { int l1,l2,l3,m1,m3,s1,s2,so,woff,cg; float alpha; };

struct L1 {
  static constexpr int NIN = 16, NOUT = 32, WN = 320, NI = 3, NWIN = 3, NU = 16, SROWB = 36;
  static constexpr InsT ins[NI] = {
    {0,0,0,16,16, 0,0, 0,   0,  0, 0.25f},
    {0,1,1,16, 2, 0,1,16, 256,  1, 0.4330127019f},
    {0,2,2,16, 2, 0,4,22, 288, 10, 0.5590169944f},
  };
  static constexpr int uT [NU] = {0,0,0,0,0,0,0,0, 1,1,1,1, 2,2,2,2};
  static constexpr int uCh[NU] = {0,1,2,3,4,5,6,7, 0,1,2,3, 0,1,2,3};
  static constexpr int uD0[NU] = {0,0,0,0,0,0,0,0, 0,0,0,0, 0,0,0,0};
  static constexpr int uND[NU] = {2,2,2,2,2,2,2,2, 4,4,4,4, 4,4,4,4};
  static constexpr int uSl[NU] = {0,1,2,3,0,1,2,3, 0,1,2,3, 0,1,2,3};
};
struct L2 {
  static constexpr int NIN = 32, NOUT = 48, WN = 424, NI = 15, NWIN = 4, NU = 31, SROWB = 68;
  static constexpr InsT ins[NI] = {
    {0,0,0,16,16, 0,0, 0,   0,  0, 0.2236067977f},
    {0,1,1,16, 2, 0,1,16, 256,  1, 0.3692744729f},
    {0,2,2,16, 2, 0,4,28, 288, 10, 0.4767312946f},
    {1,0,1, 2, 2,16,0,16, 320, 35, 0.3692744729f},
    {1,1,0, 2,16,16,1, 0, 324, 44, 0.2236067977f},
    {1,1,1, 2, 2,16,1,22, 356, 53, 0.8660254038f},
    {1,1,2, 2, 2,16,1,28, 360, 80, 0.4767312946f},
    {1,2,1, 2, 2,16,4,16, 364,125, 0.3692744729f},
    {1,2,2, 2, 2,16,4,38, 368,170, 1.1180339887f},
    {2,0,2, 2, 2,22,0,28, 372,350, 0.4767312946f},
    {2,1,1, 2, 2,22,1,16, 376,375, 0.3692744729f},
    {2,1,2, 2, 2,22,1,38, 380,420, 1.1180339887f},
    {2,2,0, 2,16,22,4, 0, 384,600, 0.2236067977f},
    {2,2,1, 2, 2,22,4,22, 416,625, 0.8660254038f},
    {2,2,2, 2, 2,22,4,28, 420,700, 0.4767312946f},
  };
  static constexpr int uT [NU] = {0,0,0,0,0,0,0,0, 1,1,1,1, 2,2,2,2, 3,4,5,6,7,8,9,10,11, 12,12,13,13,14,14};
  static constexpr int uCh[NU] = {0,1,2,3,4,5,6,7, 0,1,2,3, 0,1,2,3, 0,0,0,0,0,0,0,0,0, 0,0,0,0,0,0};
  static constexpr int uD0[NU] = {0,0,0,0,0,0,0,0, 0,0,0,0, 0,0,0,0, 0,0,0,0,0,0,0,0,0, 0,1,0,1,0,1};
  static constexpr int uND[NU] = {2,2,2,2,2,2,2,2, 4,4,4,4, 4,4,4,4, 2,2,2,2,2,2,2,2,2, 1,1,1,1,1,1};
  static constexpr int uSl[NU] = {0,1,2,3,0,1,2,3, 0,1,2,3, 0,1,2,3, 1,0,3,2,2,0,3,3,1, 2,3,2,3,0,1};
};
struct L3 {
  static constexpr int NIN = 48, NOUT = 64, WN = 216, NI = 33, NWIN = 2, NU = 44, SROWB = 100;
  static constexpr InsT ins[NI] = {
    {0,0,0,16,2, 0,0, 0,   0,  0, 0.2236067977f},
    {0,1,1,16,2, 0,1,10,  32,  1, 0.3396831102f},
    {0,2,2,16,2, 0,4,16,  64, 10, 0.4385290097f},
    {1,0,1, 2,2,16,0,10,  96, 35, 0.3396831102f},
    {1,1,0, 2,2,16,1, 0, 100, 44, 0.2236067977f},
    {1,1,1, 2,2,16,1, 4, 104, 53, 0.5477225575f},
    {1,1,2, 2,2,16,1,16, 108, 80, 0.4385290097f},
    {1,2,1, 2,2,16,4,10, 112,125, 0.3396831102f},
    {1,2,2, 2,2,16,4,26, 116,170, 0.7071067812f},
    {1,2,3, 2,2,16,4,50, 120,245, 1.0801234497f},
    {1,0,1, 2,2,22,0, 4, 124, 35, 0.5477225575f},
    {1,1,0, 2,2,22,1, 2, 128, 44, 0.5f},
    {1,1,1, 2,2,22,1,10, 132, 53, 0.3396831102f},
    {1,1,2, 2,2,22,1,26, 136, 80, 0.7071067812f},
    {1,2,1, 2,2,22,4, 4, 140,125, 0.5477225575f},
    {1,2,2, 2,2,22,4,16, 144,170, 0.4385290097f},
    {1,2,3, 2,2,22,4,36, 148,245, 1.0801234497f},
    {2,0,2, 2,2,28,0,16, 152,350, 0.4385290097f},
    {2,1,1, 2,2,28,1,10, 156,375, 0.3396831102f},
    {2,1,2, 2,2,28,1,26, 160,420, 0.7071067812f},
    {2,1,3, 2,2,28,1,50, 164,495, 1.0801234497f},
    {2,2,0, 2,2,28,4, 0, 168,600, 0.2236067977f},
    {2,2,1, 2,2,28,4, 4, 172,625, 0.5477225575f},
    {2,2,2, 2,2,28,4,16, 176,700, 0.4385290097f},
    {2,2,3, 2,2,28,4,36, 180,825, 1.0801234497f},
    {2,0,2, 2,2,38,0,26, 184,350, 0.7071067812f},
    {2,1,1, 2,2,38,1, 4, 188,375, 0.5477225575f},
    {2,1,2, 2,2,38,1,16, 192,420, 0.4385290097f},
    {2,1,3, 2,2,38,1,36, 196,495, 1.0801234497f},
    {2,2,0, 2,2,38,4, 2, 200,600, 0.5f},
    {2,2,1, 2,2,38,4,10, 204,625, 0.3396831102f},
    {2,2,2, 2,2,38,4,26, 208,700, 0.7071067812f},
    {2,2,3, 2,2,38,4,50, 212,825, 1.0801234497f},
  };
  static constexpr int uT [NU] = {0,0,0,0, 1,1,1,1, 2,2,2,2, 3,4,5,6,7,8,9,10,
                                  11,12,13,14,15,16,17,18,19,20,21,22,23, 24,24,
                                  25,26,27,28,29,30,31, 32,32};
  static constexpr int uCh[NU] = {0,1,2,3, 0,1,2,3, 0,1,2,3, 0,0,0,0,0,0,0,0,
                                  0,0,0,0,0,0,0,0,0,0,0,0,0, 0,0,
                                  0,0,0,0,0,0,0, 0,0};
  static constexpr int uD0[NU] = {0,0,0,0, 0,0,0,0, 0,0,0,0, 0,0,0,0,0,0,0,0,
                                  0,0,0,0,0,0,0,0,0,0,0,0,0, 0,1,
                                  0,0,0,0,0,0,0, 0,1};
  static constexpr int uND[NU] = {4,4,4,4, 4,4,4,4, 4,4,4,4, 2,2,2,2,2,2,2,2,
                                  2,2,2,2,2,2,2,2,2,2,2,2,2, 1,1,
                                  2,2,2,2,2,2,2, 1,1};
  static constexpr int uSl[NU] = {0,1,2,3, 3,3,3,3, 0,1,2,3, 2,3,1,2,2,1,0,2,
                                  0,2,3,0,2,0,0,1,2,1,2,3,0, 0,1,
                                  1,3,3,2,3,3,1, 2,3};
};

// ======================= TP units ==========================================

template<class LD, int SLOT, int WIN, int U>
__device__ __forceinline__ void tp_units(const char* __restrict__ wrow,
    const char* __restrict__ arow, const float* __restrict__ cgs,
    const float (&sh)[9], float (&outv)[LD::NOUT])
{
  if constexpr (U < LD::NU) {
    constexpr int T_ = LD::uT[U];
    constexpr InsT I = LD::ins[T_];
    constexpr int d1 = 2*I.l1+1, d2 = 2*I.l2+1, d3 = 2*I.l3+1;
    constexpr int UCH = (I.m3 == 16) ? 2 : (I.m1 == 16 ? 4 : 2);
    constexpr int NW = UCH * I.m3;
    constexpr int woff_ch = I.woff + LD::uCh[U] * NW;
    if constexpr (LD::uSl[U] == SLOT && woff_ch >= WIN*128 && woff_ch < WIN*128 + 128) {
      constexpr int bl = woff_ch - WIN*128;
      constexpr int D0 = LD::uD0[U];
      constexpr int ND = LD::uND[U];
      #pragma unroll
      for (int dd = 0; dd < ND; ++dd) {
        const int du = D0 + dd;
        const int u  = LD::uCh[U]*UCH + du;
        float ab[d3];
        #pragma unroll
        for (int k = 0; k < d3; ++k) ab[k] = 0.f;
        #pragma unroll
        for (int i = 0; i < d1; ++i) {
          const float ai = (float)*(const _Float16*)(arow + (I.s1 + u*d1 + i)*2);
          #pragma unroll
          for (int j = 0; j < d2; ++j) {
            const float s = ai * sh[I.s2 + j];
            #pragma unroll
            for (int k = 0; k < d3; ++k)
              ab[k] = fmaf(cgs[I.cg + (i*d2 + j)*d3 + k], s, ab[k]);
          }
        }
        #pragma unroll
        for (int wo2 = 0; wo2 < I.m3/2; ++wo2) {
          const h2 wp = *(const h2*)(wrow + (bl + du*I.m3 + 2*wo2)*2);
          const float wv0 = I.alpha * (float)wp[0];
          const float wv1 = I.alpha * (float)wp[1];
          #pragma unroll
          for (int k = 0; k < d3; ++k) {
            outv[I.so + (2*wo2  )*d3 + k] = fmaf(wv0, ab[k], outv[I.so + (2*wo2  )*d3 + k]);
            outv[I.so + (2*wo2+1)*d3 + k] = fmaf(wv1, ab[k], outv[I.so + (2*wo2+1)*d3 + k]);
          }
        }
      }
    }
    tp_units<LD, SLOT, WIN, U+1>(wrow, arow, cgs, sh, outv);
  }
}

template<class LD, int WIN>
__device__ __forceinline__ void tp_win(int slot, const char* wrow, const char* arow,
    const float* cgs, const float (&sh)[9], float (&outv)[LD::NOUT])
{
  switch (slot) {
    case 0: tp_units<LD,0,WIN,0>(wrow, arow, cgs, sh, outv); break;
    case 1: tp_units<LD,1,WIN,0>(wrow, arow, cgs, sh, outv); break;
    case 2: tp_units<LD,2,WIN,0>(wrow, arow, cgs, sh, outv); break;
    default:tp_units<LD,3,WIN,0>(wrow, arow, cgs, sh, outv); break;
  }
}

// ======================= FC2 / staging helpers =============================

template<class LD>
__device__ __forceinline__ void stage_w2f(int t, const float* __restrict__ w2,
    char* __restrict__ w2sB, int wbase, int wcols)
{
  const int hh = t >> 5, cc = t & 31;
  if (cc*4 < wcols) {
    #pragma unroll
    for (int r = 0; r < 4; ++r) {
      const int hp = hh + r*8;
      const float4 va = *(const float4*)&w2[(size_t)(2*hp  )*LD::WN + wbase + cc*4];
      const float4 vb = *(const float4*)&w2[(size_t)(2*hp+1)*LD::WN + wbase + cc*4];
      const float a0[4] = {va.x, va.y, va.z, va.w};
      const float b0[4] = {vb.x, vb.y, vb.z, vb.w};
      #pragma unroll
      for (int i = 0; i < 4; ++i) {
        h2 p; p[0] = (_Float16)a0[i]; p[1] = (_Float16)b0[i];
        *(h2*)(w2sB + hp*512 + (cc*4 + i)*4) = p;
      }
    }
  }
}

template<class LD>
__device__ __forceinline__ void fc2f(int t, const float* __restrict__ b2,
    const char* __restrict__ w2sB, const char* __restrict__ hidB,
    char* __restrict__ WsB, int wbase, int wcols)
{
  const int eg = t >> 5, cg = t & 31;
  const int e0 = eg*8, c0 = cg*4;
  if (c0 < wcols) {
    float acc[8][4];
    const float4 bv = *(const float4*)&b2[wbase + c0];
    const float bb[4] = {bv.x, bv.y, bv.z, bv.w};
    #pragma unroll
    for (int ei = 0; ei < 8; ++ei)
      #pragma unroll
      for (int ci = 0; ci < 4; ++ci) acc[ei][ci] = bb[ci];
    for (int hpb = 0; hpb < 8; ++hpb) {
      #pragma unroll
      for (int q = 0; q < 4; ++q) {
        const int hp = hpb*4 + q;
        const h8 wv = *(const h8*)(w2sB + hp*512 + c0*4);
        const h8 ha = *(const h8*)(hidB + hp*272 + e0*4);
        const h8 hb = *(const h8*)(hidB + hp*272 + e0*4 + 16);
        #pragma unroll
        for (int ei = 0; ei < 8; ++ei) {
          const h2 hv = (ei < 4) ? ((const h2*)&ha)[ei] : ((const h2*)&hb)[ei-4];
          #pragma unroll
          for (int ci = 0; ci < 4; ++ci)
            acc[ei][ci] = fdot2h(hv, ((const h2*)&wv)[ci], acc[ei][ci]);
        }
      }
    }
    #pragma unroll
    for (int ei = 0; ei < 8; ++ei) {
      h2 p0, p1;
      p0[0] = (_Float16)acc[ei][0]; p0[1] = (_Float16)acc[ei][1];
      p1[0] = (_Float16)acc[ei][2]; p1[1] = (_Float16)acc[ei][3];
      char* wp = WsB + (e0+ei)*260 + c0*2;
      *(h2*)(wp)     = p0;
      *(h2*)(wp + 4) = p1;
    }
  }
}

// ======================= window recursion ==================================

template<class LD, int W>
__device__ __forceinline__ void do_windows(int t, int slot,
    const float* __restrict__ b2, const float* __restrict__ w2,
    char* __restrict__ sm, char* __restrict__ hidB, char* __restrict__ w2sB,
    const char* __restrict__ wrow, const char* __restrict__ arow,
    const float* __restrict__ cgs, const float (&sh)[9], float (&outv)[LD::NOUT])
{
  if constexpr (W < LD::NWIN) {
    constexpr int wbase = W*128;
    constexpr int wcols = (LD::WN - wbase < 128) ? (LD::WN - wbase) : 128;
    fc2f<LD>(t, b2, w2sB, hidB, sm, wbase, wcols);
    __syncthreads();
    if constexpr (W + 1 < LD::NWIN) {
      constexpr int nbase = (W+1)*128;
      constexpr int ncols = (LD::WN - nbase < 128) ? (LD::WN - nbase) : 128;
      stage_w2f<LD>(t, w2, w2sB, nbase, ncols);
    }
    tp_win<LD, W>(slot, wrow, arow, cgs, sh, outv);
    __syncthreads();
    do_windows<LD, W+1>(t, slot, b2, w2, sm, hidB, w2sB, wrow, arow, cgs, sh, outv);
  }
}

// ======================= fused conv kernel =================================

template<class LD>
__launch_bounds__(256, 3)
__global__ void conv_fused_kernel(const float* __restrict__ node_h,
    const float* __restrict__ edge_vec, const float* __restrict__ edge_feat,
    const int* __restrict__ eidx,
    const float* __restrict__ w1, const float* __restrict__ b1,
    const float* __restrict__ w2, const float* __restrict__ b2,
    const float* __restrict__ cgsrc, float* __restrict__ tp_out)
{
  constexpr int NIN = LD::NIN, NOUT = LD::NOUT;
  constexpr int SROWB = LD::SROWB;
  constexpr int OFF_HIDS = 17408, OFF_W2S = 26112, OFF_AS = 42496;
  constexpr int OFF_CGS = OFF_AS + 64*SROWB;
  static_assert(64*(LD::NOUT + 1)*4 <= OFF_HIDS, "red region too big");
  __shared__ __align__(16) char sm[OFF_CGS + 4000];

  char* efsB = sm;                 // [32 cp][272B] fp16 ef pairs (transposed)
  char* w1sB = sm + 8704;          // [32 cp][272B]
  char* hidB = sm + OFF_HIDS;      // [32 hp][272B]
  char* w2sB = sm + OFF_W2S;       // [32 hp][512B]
  char* asB  = sm + OFF_AS;        // [64 e][SROWB]
  float* cgs = (float*)(sm + OFF_CGS);

  const int t = threadIdx.x;
  const int e0g = blockIdx.x * 64;

  // ---------- phase 0: staging (ef, w1, a, cg table, w2 window 0) ----------
  {
    const float4* efg = (const float4*)edge_feat + (size_t)e0g * 16;
    #pragma unroll
    for (int r = 0; r < 4; ++r) {
      const int f = r*256 + t;
      const float4 v = efg[f];
      const int e = f >> 4, c0 = (f & 15) * 4;
      h2 pa; pa[0] = (_Float16)v.x; pa[1] = (_Float16)v.y;
      h2 pb; pb[0] = (_Float16)v.z; pb[1] = (_Float16)v.w;
      *(h2*)(efsB + (c0>>1)*272 + e*4)     = pa;
      *(h2*)(efsB + ((c0>>1)+1)*272 + e*4) = pb;
    }
    const int cp = t >> 3, hq = t & 7, hb = hq*8;
    const float4 wa0 = *(const float4*)&w1[(size_t)(2*cp)*64 + hb];
    const float4 wa1 = *(const float4*)&w1[(size_t)(2*cp)*64 + hb + 4];
    const float4 wb0 = *(const float4*)&w1[(size_t)(2*cp+1)*64 + hb];
    const float4 wb1 = *(const float4*)&w1[(size_t)(2*cp+1)*64 + hb + 4];
    const float a0[8] = {wa0.x,wa0.y,wa0.z,wa0.w, wa1.x,wa1.y,wa1.z,wa1.w};
    const float b0[8] = {wb0.x,wb0.y,wb0.z,wb0.w, wb1.x,wb1.y,wb1.z,wb1.w};
    #pragma unroll
    for (int i = 0; i < 8; ++i) {
      h2 p; p[0] = (_Float16)a0[i]; p[1] = (_Float16)b0[i];
      *(h2*)(w1sB + cp*272 + (hb+i)*4) = p;
    }
    for (int i = t; i < 64*NIN; i += 256) {
      const int e = i / NIN, c = i - e*NIN;
      const int dst = eidx[EDGES + e0g + e];
      *(_Float16*)(asB + e*SROWB + c*2) = (_Float16)node_h[(size_t)dst*NIN + c];
    }
    for (int i = t; i < 1000; i += 256) cgs[i] = cgsrc[i];
    stage_w2f<LD>(t, w2, w2sB, 0, (LD::WN < 128) ? LD::WN : 128);
  }
  __syncthreads();

  // ---------- phase 1: FC1 (hidden = softplus(ef@w1+b1)) ----------
  {
    const int hg = t >> 4, eg2 = t & 15;
    const int h0 = hg*4, e0 = eg2*4;
    float acc[4][4];
    const float4 b1v = *(const float4*)&b1[h0];
    const float bb[4] = {b1v.x, b1v.y, b1v.z, b1v.w};
    #pragma unroll
    for (int j = 0; j < 4; ++j)
      #pragma unroll
      for (int i = 0; i < 4; ++i) acc[j][i] = bb[j];
    #pragma unroll 4
    for (int cp = 0; cp < 32; ++cp) {
      const h8 ev = *(const h8*)(efsB + cp*272 + e0*4);
      const h8 wv = *(const h8*)(w1sB + cp*272 + h0*4);
      #pragma unroll
      for (int j = 0; j < 4; ++j)
        #pragma unroll
        for (int i = 0; i < 4; ++i)
          acc[j][i] = fdot2h(((const h2*)&wv)[j], ((const h2*)&ev)[i], acc[j][i]);
    }
    #pragma unroll
    for (int i = 0; i < 4; ++i) {
      #pragma unroll
      for (int jp = 0; jp < 2; ++jp) {
        h2 p;
        p[0] = (_Float16)softplusf(acc[2*jp  ][i]);
        p[1] = (_Float16)softplusf(acc[2*jp+1][i]);
        *(h2*)(hidB + (2*hg + jp)*272 + (e0+i)*4) = p;
      }
    }
  }

  // ---------- per-edge TP state ----------
  const int slot = t >> 6;
  const int le = t & 63;
  const int eme = e0g + le;
  float sh[9];
  {
    const float vx = edge_vec[(size_t)eme*3 + 0];
    const float vy = edge_vec[(size_t)eme*3 + 1];
    const float vz = edge_vec[(size_t)eme*3 + 2];
    const float nrm = sqrtf(vx*vx + vy*vy + vz*vz);
    const float invn = 1.0f / fmaxf(nrm, 1e-12f);
    const float x = vx*invn, y = vy*invn, z = vz*invn;
    sh[0] = 1.0f;
    sh[1] = 1.7320508076f * y;
    sh[2] = 1.7320508076f * z;
    sh[3] = 1.7320508076f * x;
    sh[4] = 3.8729833462f * x * y;
    sh[5] = 3.8729833462f * y * z;
    sh[6] = 1.1180339887f * (3.0f*z*z - 1.0f);
    sh[7] = 3.8729833462f * x * z;
    sh[8] = 1.9364916731f * (x*x - y*y);
  }
  float outv[NOUT];
  #pragma unroll
  for (int o = 0; o < NOUT; ++o) outv[o] = 0.f;
  const char* wrow = sm + le * 260;
  const char* arow = asB + le * SROWB;
  __syncthreads();

  // ---------- phase 2: windows (FC2 -> Ws; TP from Ws, 4 slots) ----------
  do_windows<LD, 0>(t, slot, b2, w2, sm, hidB, w2sB, wrow, arow, cgs, sh, outv);

  // ---------- phase 3: 3-step LDS slot accumulate + coalesced-ish store ----
  constexpr int PAD = NOUT + 1;
  float* red = (float*)sm;                 // [64][PAD], reuses Ws region
  float* myrow = red + (size_t)le * PAD;
  if (slot == 3) {
    #pragma unroll
    for (int o = 0; o < NOUT; ++o) myrow[o] = outv[o];
  }
  __syncthreads();
  if (slot == 2) {
    #pragma unroll
    for (int o = 0; o < NOUT; ++o) myrow[o] += outv[o];
  }
  __syncthreads();
  if (slot == 1) {
    #pragma unroll
    for (int o = 0; o < NOUT; ++o) myrow[o] += outv[o];
  }
  __syncthreads();
  if (slot == 0) {
    float* dst = tp_out + (size_t)eme * NOUT;
    #pragma unroll
    for (int o = 0; o < NOUT; o += 4) {
      float4 v;
      v.x = myrow[o]   + outv[o];
      v.y = myrow[o+1] + outv[o+1];
      v.z = myrow[o+2] + outv[o+2];
      v.w = myrow[o+3] + outv[o+3];
      *(float4*)&dst[o] = v;
    }
  }
}

// ======================= CSR build kernels =================================

__global__ void cnt_kernel(const int* __restrict__ eidx, int* __restrict__ cnti){
  const int e = blockIdx.x * 256 + threadIdx.x;
  if (e < EDGES) atomicAdd(&cnti[eidx[e]], 1);
}

__global__ void scanA_kernel(const int* __restrict__ cnti, int* __restrict__ escan,
                             int* __restrict__ bsum){
  __shared__ int s[256];
  const int t = threadIdx.x, idx = blockIdx.x*256 + t;
  int v = (idx < NODES) ? cnti[idx] : 0;
  s[t] = v; __syncthreads();
  for (int off = 1; off < 256; off <<= 1){
    int x = (t >= off) ? s[t-off] : 0;
    __syncthreads();
    s[t] += x;
    __syncthreads();
  }
  if (idx < NODES) escan[idx] = s[t];
  if (t == 255) bsum[blockIdx.x] = s[255];
}

__global__ void scanB_kernel(const int* __restrict__ bsum, int* __restrict__ boff){
  __shared__ int s[128];
  const int t = threadIdx.x;
  int v = (t < NB_SCAN) ? bsum[t] : 0;
  s[t] = v; __syncthreads();
  for (int off = 1; off < 128; off <<= 1){
    int x = (t >= off) ? s[t-off] : 0;
    __syncthreads();
    s[t] += x;
    __syncthreads();
  }
  if (t < NB_SCAN) boff[t] = s[t] - v;   // exclusive
}

__global__ void scanC_kernel(const int* __restrict__ escan, const int* __restrict__ cnti,
                             const int* __restrict__ boff, int* __restrict__ eoff,
                             int* __restrict__ ecur){
  const int idx = blockIdx.x*256 + threadIdx.x;
  if (idx < NODES){
    const int v = escan[idx] - cnti[idx] + boff[blockIdx.x];
    eoff[idx] = v; ecur[idx] = v;
  }
  if (idx == 0) eoff[NODES] = EDGES;
}

__global__ void fill_eids_kernel(const int* __restrict__ eidx, int* __restrict__ ecur,
                                 int* __restrict__ eids){
  const int e = blockIdx.x * 256 + threadIdx.x;
  if (e < EDGES){
    const int p = atomicAdd(&ecur[eidx[e]], 1);
    eids[p] = e;
  }
}

// ======================= gather (segment mean, no atomics) =================

template<int NOUT, bool RES>
__global__ void gather_kernel(const float* __restrict__ tp_out,
    const int* __restrict__ eoff, const int* __restrict__ eids,
    const float* __restrict__ h0, float* __restrict__ out)
{
  const int node = blockIdx.x * 4 + (threadIdx.x >> 6);
  const int lane = threadIdx.x & 63;
  if (node >= NODES) return;
  const int s = eoff[node], e_end = eoff[node+1];
  if (lane < NOUT) {
    float v = 0.f;
    for (int k = s; k < e_end; ++k) {
      const int e = eids[k];
      v += tp_out[(size_t)e*NOUT + lane];
    }
    v /= fmaxf((float)(e_end - s), 1.0f);
    if (RES && lane < 16) v += h0[node*16 + lane];
    out[(size_t)node*NOUT + lane] = v;
  }
}

// ======================= small kernels =====================================

__global__ void lin_kernel(const float* __restrict__ nf, const float* __restrict__ w,
                           const float* __restrict__ b, float* __restrict__ h0){
  const int idx = blockIdx.x * 256 + threadIdx.x;
  if (idx >= NODES * 16) return;
  const int n = idx >> 4, o = idx & 15;
  const float* __restrict__ row = nf + (size_t)n * 256;
  float acc = b[o];
  for (int c = 0; c < 256; ++c) acc = fmaf(row[c], w[c*16 + o], acc);
  h0[idx] = acc;
}

// ======================= launch ============================================

extern "C" void kernel_launch(void* const* d_in, const int* in_sizes, int n_in,
                              void* d_out, int out_size, void* d_ws, size_t ws_size,
                              hipStream_t stream) {
  (void)in_sizes; (void)n_in; (void)out_size; (void)ws_size;
  const float* node_feature = (const float*)d_in[0];
  const float* edge_vec     = (const float*)d_in[1];
  const float* edge_feature = (const float*)d_in[2];
  const int*   edge_index   = (const int*)d_in[3];
  const float* lin_w = (const float*)d_in[4];
  const float* lin_b = (const float*)d_in[5];
  const float* f1w1 = (const float*)d_in[6];
  const float* f1b1 = (const float*)d_in[7];
  const float* f1w2 = (const float*)d_in[8];
  const float* f1b2 = (const float*)d_in[9];
  const float* f2w1 = (const float*)d_in[10];
  const float* f2b1 = (const float*)d_in[11];
  const float* f2w2 = (const float*)d_in[12];
  const float* f2b2 = (const float*)d_in[13];
  const float* f3w1 = (const float*)d_in[14];
  const float* f3b1 = (const float*)d_in[15];
  const float* f3w2 = (const float*)d_in[16];
  const float* f3b2 = (const float*)d_in[17];

  float* ws   = (float*)d_ws;
  float* cg   = ws;                          // 1024
  int*   cnti = (int*)(ws + 1024);           // 30000
  int*   escan= (int*)(ws + 32768);          // 30000
  int*   bsum = (int*)(ws + 65536);          // 128
  int*   boff = (int*)(ws + 65792);          // 128
  int*   eoff = (int*)(ws + 66048);          // 30001
  int*   ecur = (int*)(ws + 98304);          // 30000
  int*   eids = (int*)(ws + 131072);         // 360000
  float* h0   = ws + 524288;                 // 480000
  float* h1   = ws + 1048576;                // 960000
  float* h2p  = ws + 2097152;                // 1440000
  float* tpo  = ws + 3538944;                // 360000*64 max
  float* outp = (float*)d_out;               // 30000*64

  (void)hipMemsetAsync(cnti, 0, NODES * sizeof(int), stream);

  init_cg_kernel<<<18, 256, 0, stream>>>(cg);
  cnt_kernel<<<(EDGES + 255)/256, 256, 0, stream>>>(edge_index, cnti);
  scanA_kernel<<<NB_SCAN, 256, 0, stream>>>(cnti, escan, bsum);
  scanB_kernel<<<1, 128, 0, stream>>>(bsum, boff);
  scanC_kernel<<<NB_SCAN, 256, 0, stream>>>(escan, cnti, boff, eoff, ecur);
  fill_eids_kernel<<<(EDGES + 255)/256, 256, 0, stream>>>(edge_index, ecur, eids);
  lin_kernel<<<(NODES*16 + 255)/256, 256, 0, stream>>>(node_feature, lin_w, lin_b, h0);

  const int egrid = EDGES / 64;    // 5625, exact
  const int ggrid = (NODES + 3) / 4;

  conv_fused_kernel<L1><<<egrid, 256, 0, stream>>>(h0, edge_vec, edge_feature, edge_index,
                                                   f1w1, f1b1, f1w2, f1b2, cg, tpo);
  gather_kernel<32, true><<<ggrid, 256, 0, stream>>>(tpo, eoff, eids, h0, h1);

  conv_fused_kernel<L2><<<egrid, 256, 0, stream>>>(h1, edge_vec, edge_feature, edge_index,
                                                   f2w1, f2b1, f2w2, f2b2, cg, tpo);
  gather_kernel<48, false><<<ggrid, 256, 0, stream>>>(tpo, eoff, eids, h0, h2p);

  conv_fused_kernel<L3><<<egrid, 256, 0, stream>>>(h2p, edge_vec, edge_feature, edge_index,
                                                   f3w1, f3b1, f3w2, f3b2, cg, tpo);
  gather_kernel<64, false><<<ggrid, 256, 0, stream>>>(tpo, eoff, eids, h0, outp);
}